// Round 1
// baseline (672.759 us; speedup 1.0000x reference)
//
#include <hip/hip_runtime.h>
#include <hip/hip_bf16.h>

// ---------------------------------------------------------------------------
// AMMN_Net: dual 2-layer GCN + gated fusion head.
// Restructuring: S@(x@W) == (S@x)@W  (per-edge norm is scalar), so:
//   xa = S@x (128-dim, shared by both nets)  -> GEMM1 (both nets, combined W)
//   BN+ReLU -> ha = S@h (128-dim, both nets) -> GEMM2 (per net)
//   gather batch rows -> GEMM(Wf1)+tanh x2 -> wave-per-row head epilogue
// CSR built per call (counts -> scan -> fill) to avoid float scatter atomics.
// ---------------------------------------------------------------------------

static __device__ __forceinline__ float wred64(float v) {
#pragma unroll
  for (int m = 32; m; m >>= 1) v += __shfl_xor(v, m, 64);
  return v;
}

__global__ void k_init(int* cnt, int* cur, float* gsum, float* gsumsq,
                       int* rowptr, int n, int E) {
  int i = blockIdx.x * 256 + threadIdx.x;
  if (i < n) { cnt[i] = 0; cur[i] = 0; }
  if (i < 128) { gsum[i] = 0.f; gsumsq[i] = 0.f; }
  if (i == 0) rowptr[n] = E;
}

__global__ void k_wc1(const float* __restrict__ W1g, const float* __restrict__ b1g,
                      const float* __restrict__ W1s, const float* __restrict__ b1s,
                      float* __restrict__ wc1, float* __restrict__ bc1) {
  int idx = blockIdx.x * 256 + threadIdx.x;
  if (idx < 128 * 128) {
    int k = idx >> 7, c = idx & 127;
    wc1[idx] = (c < 64) ? W1g[k * 64 + c] : W1s[k * 64 + (c - 64)];
  }
  if (idx < 128) bc1[idx] = (idx < 64) ? b1g[idx] : b1s[idx - 64];
}

__global__ void k_count(const int* __restrict__ dst, int* __restrict__ cnt, int E) {
  int e = blockIdx.x * 256 + threadIdx.x;
  if (e < E) atomicAdd(&cnt[dst[e]], 1);
}

__global__ void k_dinv(const int* __restrict__ cnt, float* __restrict__ dinv, int n) {
  int i = blockIdx.x * 256 + threadIdx.x;
  if (i < n) dinv[i] = rsqrtf((float)(cnt[i] + 1));  // +1 self loop; deg>=1 always
}

// ---- exclusive scan of cnt[n] -> rowptr[n] (3 kernels) ----
__global__ void k_scan_a(const int* __restrict__ cnt, int* __restrict__ bsum, int n) {
  __shared__ int sh[256];
  int i = blockIdx.x * 256 + threadIdx.x;
  sh[threadIdx.x] = (i < n) ? cnt[i] : 0;
  __syncthreads();
  for (int off = 128; off > 0; off >>= 1) {
    if (threadIdx.x < off) sh[threadIdx.x] += sh[threadIdx.x + off];
    __syncthreads();
  }
  if (threadIdx.x == 0) bsum[blockIdx.x] = sh[0];
}

__global__ void k_scan_b(int* bsum, int nb) {  // nb <= 512
  __shared__ int sh[512];
  int t = threadIdx.x;
  int v = (t < nb) ? bsum[t] : 0;
  sh[t] = v;
  __syncthreads();
  for (int off = 1; off < 512; off <<= 1) {
    int add = (t >= off) ? sh[t - off] : 0;
    __syncthreads();
    sh[t] += add;
    __syncthreads();
  }
  if (t < nb) bsum[t] = sh[t] - v;  // exclusive, in place
}

__global__ void k_scan_c(const int* __restrict__ cnt, const int* __restrict__ bsum,
                         int* __restrict__ rowptr, int n) {
  __shared__ int sh[256];
  int i = blockIdx.x * 256 + threadIdx.x;
  int t = threadIdx.x;
  int v = (i < n) ? cnt[i] : 0;
  sh[t] = v;
  __syncthreads();
  for (int off = 1; off < 256; off <<= 1) {
    int add = (t >= off) ? sh[t - off] : 0;
    __syncthreads();
    sh[t] += add;
    __syncthreads();
  }
  if (i < n) rowptr[i] = bsum[blockIdx.x] + sh[t] - v;
}

__global__ void k_fill(const int* __restrict__ src, const int* __restrict__ dst,
                       const float* __restrict__ dinv, const int* __restrict__ rowptr,
                       int* __restrict__ cur, int* __restrict__ col,
                       float* __restrict__ wgt, int E) {
  int e = blockIdx.x * 256 + threadIdx.x;
  if (e < E) {
    int d = dst[e], s = src[e];
    int slot = rowptr[d] + atomicAdd(&cur[d], 1);
    col[slot] = s;
    wgt[slot] = dinv[s];
  }
}

// out[i] = dinv[i] * ( feat[i]*dinv[i] + sum_{e in(i)} feat[src_e]*dinv[src_e] )
__global__ void k_agg(const float* __restrict__ feat, float* __restrict__ out,
                      const int* __restrict__ rowptr, const int* __restrict__ col,
                      const float* __restrict__ wgt, const float* __restrict__ dinv,
                      int n) {
  int node = blockIdx.x * 8 + (threadIdx.x >> 5);
  if (node >= n) return;
  int t = threadIdx.x & 31;  // float4 lane: 32*4 = 128 features
  float di = dinv[node];
  const float4* f4 = (const float4*)feat;
  float4 sv = f4[(size_t)node * 32 + t];
  float4 acc = make_float4(sv.x * di, sv.y * di, sv.z * di, sv.w * di);
  int beg = rowptr[node], end = rowptr[node + 1];
  for (int e = beg; e < end; ++e) {
    int s = col[e];
    float w = wgt[e];
    float4 v = f4[(size_t)s * 32 + t];
    acc.x += v.x * w; acc.y += v.y * w; acc.z += v.z * w; acc.w += v.w * w;
  }
  acc.x *= di; acc.y *= di; acc.z *= di; acc.w *= di;
  ((float4*)out)[(size_t)node * 32 + t] = acc;
}

// C[r, coff:coff+NC] = A[r, koff:koff+K] @ W[K,NC] + bias, optional tanh.
// Block: 64 rows x NC cols, 256 threads, W in LDS.
template <int K, int NC, bool TANH>
__global__ __launch_bounds__(256) void k_gemm(
    const float* __restrict__ A, int lda, int koff,
    const float* __restrict__ W, const float* __restrict__ bias,
    float* __restrict__ C, int ldc, int coff, int n) {
  constexpr int CG = NC / 8;    // col groups (8 cols per thread)
  constexpr int NRG = 256 / CG; // row groups
  constexpr int RPT = 64 / NRG; // rows per thread
  __shared__ float Wl[K * NC];
  for (int idx = threadIdx.x; idx < K * NC; idx += 256) Wl[idx] = W[idx];
  __syncthreads();
  int colg = threadIdx.x % CG;
  int rgrp = threadIdx.x / CG;
  int rowBase = blockIdx.x * 64;
  const float* ap[RPT];
#pragma unroll
  for (int j = 0; j < RPT; j++) {
    int r = rowBase + rgrp + j * NRG;
    ap[j] = A + (size_t)min(r, n - 1) * lda + koff;
  }
  float acc[RPT][8];
#pragma unroll
  for (int j = 0; j < RPT; j++)
#pragma unroll
    for (int c = 0; c < 8; c++) acc[j][c] = 0.f;
  const float* w0p = &Wl[4 * colg];            // cols 4colg..+3   (banks 2-way: free)
  const float* w1p = &Wl[NC / 2 + 4 * colg];   // cols NC/2+4colg..+3
#pragma unroll 2
  for (int kk = 0; kk < K; ++kk) {
    float4 w0 = *(const float4*)(w0p + kk * NC);
    float4 w1 = *(const float4*)(w1p + kk * NC);
#pragma unroll
    for (int j = 0; j < RPT; j++) {
      float a = ap[j][kk];
      acc[j][0] += a * w0.x; acc[j][1] += a * w0.y;
      acc[j][2] += a * w0.z; acc[j][3] += a * w0.w;
      acc[j][4] += a * w1.x; acc[j][5] += a * w1.y;
      acc[j][6] += a * w1.z; acc[j][7] += a * w1.w;
    }
  }
  float b0[4] = {0, 0, 0, 0}, b1[4] = {0, 0, 0, 0};
  if (bias) {
#pragma unroll
    for (int c = 0; c < 4; c++) {
      b0[c] = bias[4 * colg + c];
      b1[c] = bias[NC / 2 + 4 * colg + c];
    }
  }
#pragma unroll
  for (int j = 0; j < RPT; j++) {
    int r = rowBase + rgrp + j * NRG;
    if (r < n) {
      float4 o0, o1;
      o0.x = acc[j][0] + b0[0]; o0.y = acc[j][1] + b0[1];
      o0.z = acc[j][2] + b0[2]; o0.w = acc[j][3] + b0[3];
      o1.x = acc[j][4] + b1[0]; o1.y = acc[j][5] + b1[1];
      o1.z = acc[j][6] + b1[2]; o1.w = acc[j][7] + b1[3];
      if (TANH) {
        o0.x = tanhf(o0.x); o0.y = tanhf(o0.y); o0.z = tanhf(o0.z); o0.w = tanhf(o0.w);
        o1.x = tanhf(o1.x); o1.y = tanhf(o1.y); o1.z = tanhf(o1.z); o1.w = tanhf(o1.w);
      }
      *(float4*)&C[(size_t)r * ldc + coff + 4 * colg] = o0;
      *(float4*)&C[(size_t)r * ldc + coff + NC / 2 + 4 * colg] = o1;
    }
  }
}

__global__ void k_bnstats(const float* __restrict__ h, float* __restrict__ gsum,
                          float* __restrict__ gsumsq, int n) {
  __shared__ float ss[256], sq[256];
  int col = threadIdx.x & 127;
  int rs = threadIdx.x >> 7;
  float s = 0.f, q = 0.f;
  for (int r = blockIdx.x * 2 + rs; r < n; r += gridDim.x * 2) {
    float v = h[(size_t)r * 128 + col];
    s += v;
    q += v * v;
  }
  ss[threadIdx.x] = s;
  sq[threadIdx.x] = q;
  __syncthreads();
  if (threadIdx.x < 128) {
    atomicAdd(&gsum[col], ss[threadIdx.x] + ss[threadIdx.x + 128]);
    atomicAdd(&gsumsq[col], sq[threadIdx.x] + sq[threadIdx.x + 128]);
  }
}

__global__ void k_bnfinal(const float* __restrict__ gsum, const float* __restrict__ gsumsq,
                          const float* __restrict__ g1g, const float* __restrict__ be1g,
                          const float* __restrict__ g1s, const float* __restrict__ be1s,
                          float* __restrict__ scale, float* __restrict__ shift, int n) {
  int c = threadIdx.x;
  if (c < 128) {
    float inv_n = 1.f / (float)n;
    float mu = gsum[c] * inv_n;
    float var = gsumsq[c] * inv_n - mu * mu;
    float gam = (c < 64) ? g1g[c] : g1s[c - 64];
    float bet = (c < 64) ? be1g[c] : be1s[c - 64];
    float sc = gam * rsqrtf(var + 1e-5f);
    scale[c] = sc;
    shift[c] = bet - mu * sc;
  }
}

__global__ void k_bnrelu(float* __restrict__ h, const float* __restrict__ scale,
                         const float* __restrict__ shift, int n4) {
  int i = blockIdx.x * 256 + threadIdx.x;
  if (i >= n4) return;
  int c4 = i & 31;
  float4 v = ((const float4*)h)[i];
  float4 sc = ((const float4*)scale)[c4];
  float4 sf = ((const float4*)shift)[c4];
  v.x = fmaxf(v.x * sc.x + sf.x, 0.f);
  v.y = fmaxf(v.y * sc.y + sf.y, 0.f);
  v.z = fmaxf(v.z * sc.z + sf.z, 0.f);
  v.w = fmaxf(v.w * sc.w + sf.w, 0.f);
  ((float4*)h)[i] = v;
}

// gen[b] = [nodes[u,0:64] | nodes[it,0:64]]; spec[b] = [nodes[u,64:128] | nodes[it,64:128]]
__global__ void k_gather(const float* __restrict__ nodes, const int* __restrict__ users,
                         const int* __restrict__ items, float* __restrict__ gen,
                         float* __restrict__ spec, int B) {
  int idx = blockIdx.x * 256 + threadIdx.x;
  if (idx >= B * 128) return;
  int b = idx >> 7, j = idx & 127;
  int node = (j < 64) ? users[b] : items[b];
  int jj = j & 63;
  gen[idx] = nodes[(size_t)node * 128 + jj];
  spec[idx] = nodes[(size_t)node * 128 + 64 + jj];
}

__global__ void k_head(const float* __restrict__ G1, const float* __restrict__ G2,
                       const float* __restrict__ gen, const float* __restrict__ Wsig,
                       const float* __restrict__ Wtc, const float* __restrict__ btc,
                       const float* __restrict__ Wp, const float* __restrict__ bp,
                       float* __restrict__ out, int B) {
  int l = threadIdx.x & 63;
  int wave = (blockIdx.x * 256 + threadIdx.x) >> 6;
  int nw = (gridDim.x * 256) >> 6;
  for (int b = wave; b < B; b += nw) {
    const float* g1 = G1 + (size_t)b * 128;
    const float* g2 = G2 + (size_t)b * 128;
    const float* gn = gen + (size_t)b * 128;
    float h1a = g1[l], h1b = g1[64 + l];   // tanh already applied in GEMM epilogue
    float h2a = g2[l], h2b = g2[64 + l];
    float ga = gn[l], gb = gn[64 + l];
    float zp = h1a * Wsig[l] + h1b * Wsig[64 + l] + h2a * Wsig[128 + l] + h2b * Wsig[192 + l];
    float z = wred64(zp);
    z = 1.f / (1.f + expf(-z));
    float fa = z * h1a + (1.f - z) * h2a;
    float fb = z * h1b + (1.f - z) * h2b;
    float p0 = wred64(fa * Wp[l * 2] + fb * Wp[(64 + l) * 2]);
    float p1 = wred64(fa * Wp[l * 2 + 1] + fb * Wp[(64 + l) * 2 + 1]);
    float t0 = wred64(ga * Wtc[l * 4] + gb * Wtc[(64 + l) * 4]);
    float t1 = wred64(ga * Wtc[l * 4 + 1] + gb * Wtc[(64 + l) * 4 + 1]);
    float t2 = wred64(ga * Wtc[l * 4 + 2] + gb * Wtc[(64 + l) * 4 + 2]);
    float t3 = wred64(ga * Wtc[l * 4 + 3] + gb * Wtc[(64 + l) * 4 + 3]);
    if (l == 0) {
      out[b * 2] = p0 + bp[0];
      out[b * 2 + 1] = p1 + bp[1];
      float* go = out + 2 * B;
      go[b * 4] = t0 + btc[0];
      go[b * 4 + 1] = t1 + btc[1];
      go[b * 4 + 2] = t2 + btc[2];
      go[b * 4 + 3] = t3 + btc[3];
    }
  }
}

extern "C" void kernel_launch(void* const* d_in, const int* in_sizes, int n_in,
                              void* d_out, int out_size, void* d_ws, size_t ws_size,
                              hipStream_t stream) {
  const float* x = (const float*)d_in[0];
  const int* ei = (const int*)d_in[1];
  const int* users = (const int*)d_in[2];
  const int* items = (const int*)d_in[3];
  const float* W1g = (const float*)d_in[4];
  const float* b1g = (const float*)d_in[5];
  const float* g1g = (const float*)d_in[6];
  const float* be1g = (const float*)d_in[7];
  const float* W2g = (const float*)d_in[8];
  const float* b2g = (const float*)d_in[9];
  const float* W1s = (const float*)d_in[10];
  const float* b1s = (const float*)d_in[11];
  const float* g1s = (const float*)d_in[12];
  const float* be1s = (const float*)d_in[13];
  const float* W2s = (const float*)d_in[14];
  const float* b2s = (const float*)d_in[15];
  const float* Wf1 = (const float*)d_in[16];
  const float* Wsig = (const float*)d_in[17];
  const float* Wtc = (const float*)d_in[18];
  const float* btc = (const float*)d_in[19];
  const float* Wp = (const float*)d_in[20];
  const float* bp = (const float*)d_in[21];

  int n = in_sizes[0] / 128;   // 100000
  int E = in_sizes[1] / 2;     // 1600000
  int B = in_sizes[2];         // 16384
  const int* srcp = ei;
  const int* dstp = ei + E;
  float* out = (float*)d_out;

  // workspace layout (~117 MB)
  char* w = (char*)d_ws;
  auto alloc = [&](size_t bytes) -> char* {
    char* p = w;
    w += (bytes + 255) & ~(size_t)255;
    return p;
  };
  float* big0 = (float*)alloc((size_t)n * 128 * 4);  // xa / ha / batch bufs
  float* big1 = (float*)alloc((size_t)n * 128 * 4);  // h / nodes
  int* col = (int*)alloc((size_t)E * 4);
  float* wgt = (float*)alloc((size_t)E * 4);
  int* cnt = (int*)alloc((size_t)n * 4);
  int* cur = (int*)alloc((size_t)n * 4);
  int* rowptr = (int*)alloc((size_t)(n + 1) * 4);
  float* dinv = (float*)alloc((size_t)n * 4);
  float* wc1 = (float*)alloc(128 * 128 * 4);
  float* bc1 = (float*)alloc(512);
  float* gsum = (float*)alloc(512);
  float* gsumsq = (float*)alloc(512);
  float* scale = (float*)alloc(512);
  float* shift = (float*)alloc(512);
  int* bsum = (int*)alloc(512 * 4);

  int nb = (n + 255) / 256;  // 391 (must be <= 512 for k_scan_b)
  int eb = (E + 255) / 256;

  k_init<<<nb, 256, 0, stream>>>(cnt, cur, gsum, gsumsq, rowptr, n, E);
  k_wc1<<<64, 256, 0, stream>>>(W1g, b1g, W1s, b1s, wc1, bc1);
  k_count<<<eb, 256, 0, stream>>>(dstp, cnt, E);
  k_dinv<<<nb, 256, 0, stream>>>(cnt, dinv, n);
  k_scan_a<<<nb, 256, 0, stream>>>(cnt, bsum, n);
  k_scan_b<<<1, 512, 0, stream>>>(bsum, nb);
  k_scan_c<<<nb, 256, 0, stream>>>(cnt, bsum, rowptr, n);
  k_fill<<<eb, 256, 0, stream>>>(srcp, dstp, dinv, rowptr, cur, col, wgt, E);

  // layer 1: xa = S@x ; h = xa @ [W1g|W1s] + [b1g|b1s]
  k_agg<<<(n + 7) / 8, 256, 0, stream>>>(x, big0, rowptr, col, wgt, dinv, n);
  k_gemm<128, 128, false><<<(n + 63) / 64, 256, 0, stream>>>(big0, 128, 0, wc1, bc1, big1, 128, 0, n);

  // BN (training-mode, biased var) + ReLU, in place
  k_bnstats<<<512, 256, 0, stream>>>(big1, gsum, gsumsq, n);
  k_bnfinal<<<1, 128, 0, stream>>>(gsum, gsumsq, g1g, be1g, g1s, be1s, scale, shift, n);
  k_bnrelu<<<(n * 32 + 255) / 256, 256, 0, stream>>>(big1, scale, shift, n * 32);

  // layer 2: ha = S@h ; nodes = [ha_g@W2g+b2g | ha_s@W2s+b2s]
  k_agg<<<(n + 7) / 8, 256, 0, stream>>>(big1, big0, rowptr, col, wgt, dinv, n);
  k_gemm<64, 64, false><<<(n + 63) / 64, 256, 0, stream>>>(big0, 128, 0, W2g, b2g, big1, 128, 0, n);
  k_gemm<64, 64, false><<<(n + 63) / 64, 256, 0, stream>>>(big0, 128, 64, W2s, b2s, big1, 128, 64, n);

  // head: gather batch rows, two tanh-GEMMs, fused epilogue
  float* gen = big0;
  float* spec = big0 + (size_t)B * 128;
  float* G1 = big0 + (size_t)2 * B * 128;
  float* G2 = big0 + (size_t)3 * B * 128;
  k_gather<<<(B * 128 + 255) / 256, 256, 0, stream>>>(big1, users, items, gen, spec, B);
  k_gemm<128, 128, true><<<(B + 63) / 64, 256, 0, stream>>>(gen, 128, 0, Wf1, (const float*)nullptr, G1, 128, 0, B);
  k_gemm<128, 128, true><<<(B + 63) / 64, 256, 0, stream>>>(spec, 128, 0, Wf1, (const float*)nullptr, G2, 128, 0, B);
  k_head<<<2048, 256, 0, stream>>>(G1, G2, gen, Wsig, Wtc, btc, Wp, bp, out, B);
}

// Round 2
// 529.881 us; speedup vs baseline: 1.2696x; 1.2696x over previous
//
#include <hip/hip_runtime.h>
#include <hip/hip_bf16.h>

// ---------------------------------------------------------------------------
// AMMN_Net: dual 2-layer GCN + gated fusion head.
//   xa = S@x (128-dim, shared)  -> GEMM1 (combined [W1g|W1s])
//   BN+ReLU (writes bf16) -> ha = S@h -> GEMM2 per net
//   gather batch rows -> GEMM(Wf1)+tanh x2 -> wave-per-row head epilogue
// R2: aggregation gathers read bf16 rows (halves the 819 MB/layer gather
// traffic), edge loop unrolled x4 for MLP, GEMM A-loads vectorized float4.
// ---------------------------------------------------------------------------

static __device__ __forceinline__ float wred64(float v) {
#pragma unroll
  for (int m = 32; m; m >>= 1) v += __shfl_xor(v, m, 64);
  return v;
}

static __device__ __forceinline__ unsigned short f2bf(float f) {
  unsigned u = __float_as_uint(f);
  unsigned r = (u + 0x7fffu + ((u >> 16) & 1u)) >> 16;  // RNE
  return (unsigned short)r;
}
static __device__ __forceinline__ unsigned packbf(float a, float b) {
  return (unsigned)f2bf(a) | ((unsigned)f2bf(b) << 16);
}
static __device__ __forceinline__ float bflo(unsigned u) {
  return __uint_as_float(u << 16);
}
static __device__ __forceinline__ float bfhi(unsigned u) {
  return __uint_as_float(u & 0xffff0000u);
}

__global__ void k_init(int* cnt, int* cur, float* gsum, float* gsumsq,
                       int* rowptr, int n, int E) {
  int i = blockIdx.x * 256 + threadIdx.x;
  if (i < n) { cnt[i] = 0; cur[i] = 0; }
  if (i < 128) { gsum[i] = 0.f; gsumsq[i] = 0.f; }
  if (i == 0) rowptr[n] = E;
}

__global__ void k_wc1(const float* __restrict__ W1g, const float* __restrict__ b1g,
                      const float* __restrict__ W1s, const float* __restrict__ b1s,
                      float* __restrict__ wc1, float* __restrict__ bc1) {
  int idx = blockIdx.x * 256 + threadIdx.x;
  if (idx < 128 * 128) {
    int k = idx >> 7, c = idx & 127;
    wc1[idx] = (c < 64) ? W1g[k * 64 + c] : W1s[k * 64 + (c - 64)];
  }
  if (idx < 128) bc1[idx] = (idx < 64) ? b1g[idx] : b1s[idx - 64];
}

// fp32 [n*128] -> bf16 packed pairs [n*64]
__global__ void k_tobf16(const float* __restrict__ in, unsigned* __restrict__ outb,
                         int n8) {  // n8 = n*128/8
  int i = blockIdx.x * 256 + threadIdx.x;
  if (i >= n8) return;
  const float4* f4 = (const float4*)in;
  float4 a = f4[i * 2], b = f4[i * 2 + 1];
  uint4 o;
  o.x = packbf(a.x, a.y);
  o.y = packbf(a.z, a.w);
  o.z = packbf(b.x, b.y);
  o.w = packbf(b.z, b.w);
  ((uint4*)outb)[i] = o;
}

__global__ void k_count(const int* __restrict__ dst, int* __restrict__ cnt, int E) {
  int e = blockIdx.x * 256 + threadIdx.x;
  if (e < E) atomicAdd(&cnt[dst[e]], 1);
}

__global__ void k_dinv(const int* __restrict__ cnt, float* __restrict__ dinv, int n) {
  int i = blockIdx.x * 256 + threadIdx.x;
  if (i < n) dinv[i] = rsqrtf((float)(cnt[i] + 1));  // +1 self loop
}

// ---- exclusive scan of cnt[n] -> rowptr[n] ----
__global__ void k_scan_a(const int* __restrict__ cnt, int* __restrict__ bsum, int n) {
  __shared__ int sh[256];
  int i = blockIdx.x * 256 + threadIdx.x;
  sh[threadIdx.x] = (i < n) ? cnt[i] : 0;
  __syncthreads();
  for (int off = 128; off > 0; off >>= 1) {
    if (threadIdx.x < off) sh[threadIdx.x] += sh[threadIdx.x + off];
    __syncthreads();
  }
  if (threadIdx.x == 0) bsum[blockIdx.x] = sh[0];
}

__global__ void k_scan_b(int* bsum, int nb) {  // nb <= 512
  __shared__ int sh[512];
  int t = threadIdx.x;
  int v = (t < nb) ? bsum[t] : 0;
  sh[t] = v;
  __syncthreads();
  for (int off = 1; off < 512; off <<= 1) {
    int add = (t >= off) ? sh[t - off] : 0;
    __syncthreads();
    sh[t] += add;
    __syncthreads();
  }
  if (t < nb) bsum[t] = sh[t] - v;
}

__global__ void k_scan_c(const int* __restrict__ cnt, const int* __restrict__ bsum,
                         int* __restrict__ rowptr, int n) {
  __shared__ int sh[256];
  int i = blockIdx.x * 256 + threadIdx.x;
  int t = threadIdx.x;
  int v = (i < n) ? cnt[i] : 0;
  sh[t] = v;
  __syncthreads();
  for (int off = 1; off < 256; off <<= 1) {
    int add = (t >= off) ? sh[t - off] : 0;
    __syncthreads();
    sh[t] += add;
    __syncthreads();
  }
  if (i < n) rowptr[i] = bsum[blockIdx.x] + sh[t] - v;
}

__global__ void k_fill(const int* __restrict__ src, const int* __restrict__ dst,
                       const float* __restrict__ dinv, const int* __restrict__ rowptr,
                       int* __restrict__ cur, int* __restrict__ col,
                       float* __restrict__ wgt, int E) {
  int e = blockIdx.x * 256 + threadIdx.x;
  if (e < E) {
    int d = dst[e], s = src[e];
    int slot = rowptr[d] + atomicAdd(&cur[d], 1);
    col[slot] = s;
    wgt[slot] = dinv[s];
  }
}

// out[i] = dinv[i] * ( featb[i]*dinv[i] + sum_e featb[col_e]*wgt_e ), bf16 gathers
__global__ void k_agg(const unsigned* __restrict__ featb, float* __restrict__ out,
                      const int* __restrict__ rowptr, const int* __restrict__ col,
                      const float* __restrict__ wgt, const float* __restrict__ dinv,
                      int n) {
  int node = blockIdx.x * 8 + (threadIdx.x >> 5);
  if (node >= n) return;
  int t = threadIdx.x & 31;  // uint2 lane: 32*4 bf16 = 128 feats
  const uint2* f2 = (const uint2*)featb;
  float di = dinv[node];
  uint2 sv = f2[(size_t)node * 32 + t];
  float4 acc;
  acc.x = bflo(sv.x) * di; acc.y = bfhi(sv.x) * di;
  acc.z = bflo(sv.y) * di; acc.w = bfhi(sv.y) * di;
  int beg = rowptr[node], end = rowptr[node + 1];
  int e = beg;
  int end4 = beg + ((end - beg) & ~3);
  for (; e < end4; e += 4) {
    int s0 = col[e], s1 = col[e + 1], s2 = col[e + 2], s3 = col[e + 3];
    float w0 = wgt[e], w1 = wgt[e + 1], w2 = wgt[e + 2], w3 = wgt[e + 3];
    uint2 v0 = f2[(size_t)s0 * 32 + t];
    uint2 v1 = f2[(size_t)s1 * 32 + t];
    uint2 v2 = f2[(size_t)s2 * 32 + t];
    uint2 v3 = f2[(size_t)s3 * 32 + t];
    acc.x += bflo(v0.x) * w0; acc.y += bfhi(v0.x) * w0;
    acc.z += bflo(v0.y) * w0; acc.w += bfhi(v0.y) * w0;
    acc.x += bflo(v1.x) * w1; acc.y += bfhi(v1.x) * w1;
    acc.z += bflo(v1.y) * w1; acc.w += bfhi(v1.y) * w1;
    acc.x += bflo(v2.x) * w2; acc.y += bfhi(v2.x) * w2;
    acc.z += bflo(v2.y) * w2; acc.w += bfhi(v2.y) * w2;
    acc.x += bflo(v3.x) * w3; acc.y += bfhi(v3.x) * w3;
    acc.z += bflo(v3.y) * w3; acc.w += bfhi(v3.y) * w3;
  }
  for (; e < end; ++e) {
    int s = col[e];
    float w = wgt[e];
    uint2 v = f2[(size_t)s * 32 + t];
    acc.x += bflo(v.x) * w; acc.y += bfhi(v.x) * w;
    acc.z += bflo(v.y) * w; acc.w += bfhi(v.y) * w;
  }
  acc.x *= di; acc.y *= di; acc.z *= di; acc.w *= di;
  ((float4*)out)[(size_t)node * 32 + t] = acc;
}

// C[r, coff:coff+NC] = A[r, koff:koff+K] @ W[K,NC] + bias, optional tanh.
template <int K, int NC, bool TANH>
__global__ __launch_bounds__(256) void k_gemm(
    const float* __restrict__ A, int lda, int koff,
    const float* __restrict__ W, const float* __restrict__ bias,
    float* __restrict__ C, int ldc, int coff, int n) {
  constexpr int CG = NC / 8;
  constexpr int NRG = 256 / CG;
  constexpr int RPT = 64 / NRG;
  __shared__ float Wl[K * NC];
  for (int idx = threadIdx.x; idx < K * NC; idx += 256) Wl[idx] = W[idx];
  __syncthreads();
  int colg = threadIdx.x % CG;
  int rgrp = threadIdx.x / CG;
  int rowBase = blockIdx.x * 64;
  const float* ap[RPT];
#pragma unroll
  for (int j = 0; j < RPT; j++) {
    int r = rowBase + rgrp + j * NRG;
    ap[j] = A + (size_t)min(r, n - 1) * lda + koff;
  }
  float acc[RPT][8];
#pragma unroll
  for (int j = 0; j < RPT; j++)
#pragma unroll
    for (int c = 0; c < 8; c++) acc[j][c] = 0.f;
  const float* w0p = &Wl[4 * colg];
  const float* w1p = &Wl[NC / 2 + 4 * colg];
#pragma unroll 2
  for (int k4 = 0; k4 < K / 4; ++k4) {
    float4 av[RPT];
#pragma unroll
    for (int j = 0; j < RPT; j++) av[j] = *(const float4*)(ap[j] + 4 * k4);
#pragma unroll
    for (int kk = 0; kk < 4; ++kk) {
      int kr = 4 * k4 + kk;
      float4 w0 = *(const float4*)(w0p + kr * NC);
      float4 w1 = *(const float4*)(w1p + kr * NC);
#pragma unroll
      for (int j = 0; j < RPT; j++) {
        float a = ((const float*)&av[j])[kk];
        acc[j][0] += a * w0.x; acc[j][1] += a * w0.y;
        acc[j][2] += a * w0.z; acc[j][3] += a * w0.w;
        acc[j][4] += a * w1.x; acc[j][5] += a * w1.y;
        acc[j][6] += a * w1.z; acc[j][7] += a * w1.w;
      }
    }
  }
  float b0[4] = {0, 0, 0, 0}, b1[4] = {0, 0, 0, 0};
  if (bias) {
#pragma unroll
    for (int c = 0; c < 4; c++) {
      b0[c] = bias[4 * colg + c];
      b1[c] = bias[NC / 2 + 4 * colg + c];
    }
  }
#pragma unroll
  for (int j = 0; j < RPT; j++) {
    int r = rowBase + rgrp + j * NRG;
    if (r < n) {
      float4 o0, o1;
      o0.x = acc[j][0] + b0[0]; o0.y = acc[j][1] + b0[1];
      o0.z = acc[j][2] + b0[2]; o0.w = acc[j][3] + b0[3];
      o1.x = acc[j][4] + b1[0]; o1.y = acc[j][5] + b1[1];
      o1.z = acc[j][6] + b1[2]; o1.w = acc[j][7] + b1[3];
      if (TANH) {
        o0.x = tanhf(o0.x); o0.y = tanhf(o0.y); o0.z = tanhf(o0.z); o0.w = tanhf(o0.w);
        o1.x = tanhf(o1.x); o1.y = tanhf(o1.y); o1.z = tanhf(o1.z); o1.w = tanhf(o1.w);
      }
      *(float4*)&C[(size_t)r * ldc + coff + 4 * colg] = o0;
      *(float4*)&C[(size_t)r * ldc + coff + NC / 2 + 4 * colg] = o1;
    }
  }
}

__global__ void k_bnstats(const float* __restrict__ h, float* __restrict__ gsum,
                          float* __restrict__ gsumsq, int n) {
  __shared__ float ss[256], sq[256];
  int col = threadIdx.x & 127;
  int rs = threadIdx.x >> 7;
  float s = 0.f, q = 0.f;
  for (int r = blockIdx.x * 2 + rs; r < n; r += gridDim.x * 2) {
    float v = h[(size_t)r * 128 + col];
    s += v;
    q += v * v;
  }
  ss[threadIdx.x] = s;
  sq[threadIdx.x] = q;
  __syncthreads();
  if (threadIdx.x < 128) {
    atomicAdd(&gsum[col], ss[threadIdx.x] + ss[threadIdx.x + 128]);
    atomicAdd(&gsumsq[col], sq[threadIdx.x] + sq[threadIdx.x + 128]);
  }
}

__global__ void k_bnfinal(const float* __restrict__ gsum, const float* __restrict__ gsumsq,
                          const float* __restrict__ g1g, const float* __restrict__ be1g,
                          const float* __restrict__ g1s, const float* __restrict__ be1s,
                          float* __restrict__ scale, float* __restrict__ shift, int n) {
  int c = threadIdx.x;
  if (c < 128) {
    float inv_n = 1.f / (float)n;
    float mu = gsum[c] * inv_n;
    float var = gsumsq[c] * inv_n - mu * mu;
    float gam = (c < 64) ? g1g[c] : g1s[c - 64];
    float bet = (c < 64) ? be1g[c] : be1s[c - 64];
    float sc = gam * rsqrtf(var + 1e-5f);
    scale[c] = sc;
    shift[c] = bet - mu * sc;
  }
}

// BN+ReLU, fp32 in -> bf16 packed out
__global__ void k_bnrelu(const float* __restrict__ h, const float* __restrict__ scale,
                         const float* __restrict__ shift, unsigned* __restrict__ hb,
                         int n4) {  // n4 = n*32 float4-groups
  int i = blockIdx.x * 256 + threadIdx.x;
  if (i >= n4) return;
  int c4 = i & 31;
  float4 v = ((const float4*)h)[i];
  float4 sc = ((const float4*)scale)[c4];
  float4 sf = ((const float4*)shift)[c4];
  v.x = fmaxf(v.x * sc.x + sf.x, 0.f);
  v.y = fmaxf(v.y * sc.y + sf.y, 0.f);
  v.z = fmaxf(v.z * sc.z + sf.z, 0.f);
  v.w = fmaxf(v.w * sc.w + sf.w, 0.f);
  uint2 o;
  o.x = packbf(v.x, v.y);
  o.y = packbf(v.z, v.w);
  ((uint2*)hb)[i] = o;
}

__global__ void k_gather(const float* __restrict__ nodes, const int* __restrict__ users,
                         const int* __restrict__ items, float* __restrict__ gen,
                         float* __restrict__ spec, int B) {
  int idx = blockIdx.x * 256 + threadIdx.x;
  if (idx >= B * 128) return;
  int b = idx >> 7, j = idx & 127;
  int node = (j < 64) ? users[b] : items[b];
  int jj = j & 63;
  gen[idx] = nodes[(size_t)node * 128 + jj];
  spec[idx] = nodes[(size_t)node * 128 + 64 + jj];
}

__global__ void k_head(const float* __restrict__ G1, const float* __restrict__ G2,
                       const float* __restrict__ gen, const float* __restrict__ Wsig,
                       const float* __restrict__ Wtc, const float* __restrict__ btc,
                       const float* __restrict__ Wp, const float* __restrict__ bp,
                       float* __restrict__ out, int B) {
  int l = threadIdx.x & 63;
  int wave = (blockIdx.x * 256 + threadIdx.x) >> 6;
  int nw = (gridDim.x * 256) >> 6;
  for (int b = wave; b < B; b += nw) {
    const float* g1 = G1 + (size_t)b * 128;
    const float* g2 = G2 + (size_t)b * 128;
    const float* gn = gen + (size_t)b * 128;
    float h1a = g1[l], h1b = g1[64 + l];
    float h2a = g2[l], h2b = g2[64 + l];
    float ga = gn[l], gb = gn[64 + l];
    float zp = h1a * Wsig[l] + h1b * Wsig[64 + l] + h2a * Wsig[128 + l] + h2b * Wsig[192 + l];
    float z = wred64(zp);
    z = 1.f / (1.f + expf(-z));
    float fa = z * h1a + (1.f - z) * h2a;
    float fb = z * h1b + (1.f - z) * h2b;
    float p0 = wred64(fa * Wp[l * 2] + fb * Wp[(64 + l) * 2]);
    float p1 = wred64(fa * Wp[l * 2 + 1] + fb * Wp[(64 + l) * 2 + 1]);
    float t0 = wred64(ga * Wtc[l * 4] + gb * Wtc[(64 + l) * 4]);
    float t1 = wred64(ga * Wtc[l * 4 + 1] + gb * Wtc[(64 + l) * 4 + 1]);
    float t2 = wred64(ga * Wtc[l * 4 + 2] + gb * Wtc[(64 + l) * 4 + 2]);
    float t3 = wred64(ga * Wtc[l * 4 + 3] + gb * Wtc[(64 + l) * 4 + 3]);
    if (l == 0) {
      out[b * 2] = p0 + bp[0];
      out[b * 2 + 1] = p1 + bp[1];
      float* go = out + 2 * B;
      go[b * 4] = t0 + btc[0];
      go[b * 4 + 1] = t1 + btc[1];
      go[b * 4 + 2] = t2 + btc[2];
      go[b * 4 + 3] = t3 + btc[3];
    }
  }
}

extern "C" void kernel_launch(void* const* d_in, const int* in_sizes, int n_in,
                              void* d_out, int out_size, void* d_ws, size_t ws_size,
                              hipStream_t stream) {
  const float* x = (const float*)d_in[0];
  const int* ei = (const int*)d_in[1];
  const int* users = (const int*)d_in[2];
  const int* items = (const int*)d_in[3];
  const float* W1g = (const float*)d_in[4];
  const float* b1g = (const float*)d_in[5];
  const float* g1g = (const float*)d_in[6];
  const float* be1g = (const float*)d_in[7];
  const float* W2g = (const float*)d_in[8];
  const float* b2g = (const float*)d_in[9];
  const float* W1s = (const float*)d_in[10];
  const float* b1s = (const float*)d_in[11];
  const float* g1s = (const float*)d_in[12];
  const float* be1s = (const float*)d_in[13];
  const float* W2s = (const float*)d_in[14];
  const float* b2s = (const float*)d_in[15];
  const float* Wf1 = (const float*)d_in[16];
  const float* Wsig = (const float*)d_in[17];
  const float* Wtc = (const float*)d_in[18];
  const float* btc = (const float*)d_in[19];
  const float* Wp = (const float*)d_in[20];
  const float* bp = (const float*)d_in[21];

  int n = in_sizes[0] / 128;   // 100000
  int E = in_sizes[1] / 2;     // 1600000
  int B = in_sizes[2];         // 16384
  const int* srcp = ei;
  const int* dstp = ei + E;
  float* out = (float*)d_out;

  char* w = (char*)d_ws;
  auto alloc = [&](size_t bytes) -> char* {
    char* p = w;
    w += (bytes + 255) & ~(size_t)255;
    return p;
  };
  float* big0 = (float*)alloc((size_t)n * 128 * 4);     // xa / ha / batch bufs
  float* big1 = (float*)alloc((size_t)n * 128 * 4);     // h / nodes
  unsigned* bff = (unsigned*)alloc((size_t)n * 128 * 2); // bf16 feat (x, then h)
  int* col = (int*)alloc((size_t)E * 4);
  float* wgt = (float*)alloc((size_t)E * 4);
  int* cnt = (int*)alloc((size_t)n * 4);
  int* cur = (int*)alloc((size_t)n * 4);
  int* rowptr = (int*)alloc((size_t)(n + 1) * 4);
  float* dinv = (float*)alloc((size_t)n * 4);
  float* wc1 = (float*)alloc(128 * 128 * 4);
  float* bc1 = (float*)alloc(512);
  float* gsum = (float*)alloc(512);
  float* gsumsq = (float*)alloc(512);
  float* scale = (float*)alloc(512);
  float* shift = (float*)alloc(512);
  int* bsum = (int*)alloc(512 * 4);

  int nb = (n + 255) / 256;  // 391 <= 512
  int eb = (E + 255) / 256;

  k_init<<<nb, 256, 0, stream>>>(cnt, cur, gsum, gsumsq, rowptr, n, E);
  k_wc1<<<64, 256, 0, stream>>>(W1g, b1g, W1s, b1s, wc1, bc1);
  k_tobf16<<<(n * 16 + 255) / 256, 256, 0, stream>>>(x, bff, n * 16);
  k_count<<<eb, 256, 0, stream>>>(dstp, cnt, E);
  k_dinv<<<nb, 256, 0, stream>>>(cnt, dinv, n);
  k_scan_a<<<nb, 256, 0, stream>>>(cnt, bsum, n);
  k_scan_b<<<1, 512, 0, stream>>>(bsum, nb);
  k_scan_c<<<nb, 256, 0, stream>>>(cnt, bsum, rowptr, n);
  k_fill<<<eb, 256, 0, stream>>>(srcp, dstp, dinv, rowptr, cur, col, wgt, E);

  // layer 1
  k_agg<<<(n + 7) / 8, 256, 0, stream>>>(bff, big0, rowptr, col, wgt, dinv, n);
  k_gemm<128, 128, false><<<(n + 63) / 64, 256, 0, stream>>>(big0, 128, 0, wc1, bc1, big1, 128, 0, n);

  // BN + ReLU -> bf16 hidden
  k_bnstats<<<512, 256, 0, stream>>>(big1, gsum, gsumsq, n);
  k_bnfinal<<<1, 128, 0, stream>>>(gsum, gsumsq, g1g, be1g, g1s, be1s, scale, shift, n);
  k_bnrelu<<<(n * 32 + 255) / 256, 256, 0, stream>>>(big1, scale, shift, bff, n * 32);

  // layer 2
  k_agg<<<(n + 7) / 8, 256, 0, stream>>>(bff, big0, rowptr, col, wgt, dinv, n);
  k_gemm<64, 64, false><<<(n + 63) / 64, 256, 0, stream>>>(big0, 128, 0, W2g, b2g, big1, 128, 0, n);
  k_gemm<64, 64, false><<<(n + 63) / 64, 256, 0, stream>>>(big0, 128, 64, W2s, b2s, big1, 128, 64, n);

  // head
  float* gen = big0;
  float* spec = big0 + (size_t)B * 128;
  float* G1 = big0 + (size_t)2 * B * 128;
  float* G2 = big0 + (size_t)3 * B * 128;
  k_gather<<<(B * 128 + 255) / 256, 256, 0, stream>>>(big1, users, items, gen, spec, B);
  k_gemm<128, 128, true><<<(B + 63) / 64, 256, 0, stream>>>(gen, 128, 0, Wf1, (const float*)nullptr, G1, 128, 0, B);
  k_gemm<128, 128, true><<<(B + 63) / 64, 256, 0, stream>>>(spec, 128, 0, Wf1, (const float*)nullptr, G2, 128, 0, B);
  k_head<<<2048, 256, 0, stream>>>(G1, G2, gen, Wsig, Wtc, btc, Wp, bp, out, B);
}